// Round 19
// baseline (742.019 us; speedup 1.0000x reference)
//
#include <hip/hip_runtime.h>
#include <cstdint>

typedef __attribute__((ext_vector_type(8))) short short8;
typedef __attribute__((ext_vector_type(4))) float f32x4;

__device__ __forceinline__ ushort f2bf(float x){
    uint32_t u = __float_as_uint(x);
    u = (u + 0x7FFFu + ((u >> 16) & 1u)) >> 16;
    return (ushort)u;
}
__device__ __forceinline__ ushort f2h(float x){
    _Float16 h = (_Float16)x;
    return __builtin_bit_cast(ushort, h);
}

// -------- kernel 1: weight conversion (fp16 W + W1, bf16 W2 + embed) ------
__global__ void k_conv(const float* __restrict__ W1, const float* __restrict__ W2,
                       const float* __restrict__ Emb, const float* __restrict__ W,
                       ushort* __restrict__ W1h, ushort* __restrict__ W2b,
                       ushort* __restrict__ Eb, ushort* __restrict__ Wh){
    int i = blockIdx.x * 256 + threadIdx.x;   // grid 256 -> 65536
    W1h[i] = f2h(W1[i]);
    W2b[i] = f2bf(W2[i]);
    Eb[i]  = f2bf(Emb[i]);
    Wh[i]  = f2h(W[i]);
}

// -------- kernel 2: proj[v][h] = sum_e embed[v,e]*W_in[h,e]  (fp32) -------
__global__ void k_proj(const float* __restrict__ emb, const float* __restrict__ Win,
                       float* __restrict__ proj){
    __shared__ __align__(16) float se[256];
    int v = blockIdx.x, h = threadIdx.x;
    se[h] = emb[v*256 + h];
    __syncthreads();
    const float* wr = Win + h*256;
    float a0=0.f,a1=0.f,a2=0.f,a3=0.f;
    #pragma unroll
    for (int e = 0; e < 256; e += 4){
        float4 w = *(const float4*)(wr + e);
        a0 = fmaf(w.x, se[e+0], a0);
        a1 = fmaf(w.y, se[e+1], a1);
        a2 = fmaf(w.z, se[e+2], a2);
        a3 = fmaf(w.w, se[e+3], a3);
    }
    proj[v*256 + h] = (a0+a1)+(a2+a3);
}

// ------------- kernel 3: ESN recurrence via MFMA, fp16 W+state ------------
// 256 blocks = (segment s in [0,32)) x (batch group pg in [0,8)), 1 block/CU.
// warmup=128 HW-verified (r13/r14/r17). Critical path 192 steps (~130us).
__global__ __launch_bounds__(512, 2) void k_recur(const int* __restrict__ idx,
        const ushort* Wh, const float* proj, ushort* hs){
    __shared__ __align__(16) char Hl[2][8192];   // fp16 H[16][256], dbuf, swizzled
    const int tid  = threadIdx.x;
    const int wid  = tid >> 6;
    const int lane = tid & 63;
    const int lr   = lane & 15;        // batch col / A-row-in-tile
    const int lg   = lane >> 4;
    const int seg  = blockIdx.x >> 3;  // time segment 0..31
    const int pg   = blockIdx.x & 7;   // batch group 0..7
    const int t0   = (64*seg - 128 > 0) ? (64*seg - 128) : 0;
    const int t1   = 64*seg + 64;
    const int tw   = 64*seg;           // first written step

    // A-frags: W rows for tiles n0=2*wid, n1=2*wid+1 (fp16, 16 frags = 64 VGPR)
    short8 A0[8], A1[8];
    {
        const char* wb = (const char*)Wh + (32*wid + lr)*512 + lg*16;
        #pragma unroll
        for (int kk = 0; kk < 8; ++kk){
            A0[kk] = __builtin_bit_cast(short8, *(const uint4*)(wb + kk*64));
            A1[kk] = __builtin_bit_cast(short8, *(const uint4*)(wb + 16*512 + kk*64));
        }
    }

    char* Hb = &Hl[0][0];
    *(uint4*)(Hb + tid*16) = uint4{0,0,0,0};     // zero buffer 0 (8 KB)
    __syncthreads();

    const int mybat = pg*16 + lr;
    const int64_t idxbase = (int64_t)mybat * 2048;
    ushort* hsrow = hs + (size_t)mybat * 2048 * 256;
    const int hd0 = 32*wid + lg*4;               // tile0 quad base hdim
    const int hd1 = hd0 + 16;

    float hp0[4] = {0.f,0.f,0.f,0.f}, hp1[4] = {0.f,0.f,0.f,0.f};

    // prologue: u for t0, token for t0+1
    int tok  = idx[idxbase + t0];
    int tok2 = idx[idxbase + ((t0+1 < 2048) ? t0+1 : 2047)];
    f32x4 u0 = *(const f32x4*)(proj + tok*256 + hd0);
    f32x4 u1 = *(const f32x4*)(proj + tok*256 + hd1);

#define STEP(T, RO, WO)                                                        \
    {                                                                          \
        int tok3 = idx[idxbase + (((T)+2 < 2048) ? (T)+2 : 2047)];             \
        f32x4 ac0 = u0, ac1 = u1;   /* C-init = input projection */            \
        f32x4 bc0 = {0.f,0.f,0.f,0.f}, bc1 = {0.f,0.f,0.f,0.f};                \
        _Pragma("unroll")                                                      \
        for (int kk = 0; kk < 4; ++kk){                                        \
            int ra = ((RO) + lr*512 + kk*64 + lg*16) ^ (lr << 4);              \
            short8 Bf = __builtin_bit_cast(short8, *(const uint4*)(Hb + ra));  \
            ac0 = __builtin_amdgcn_mfma_f32_16x16x32_f16(A0[kk], Bf, ac0, 0,0,0);\
            ac1 = __builtin_amdgcn_mfma_f32_16x16x32_f16(A1[kk], Bf, ac1, 0,0,0);\
        }                                                                      \
        _Pragma("unroll")                                                      \
        for (int kk = 4; kk < 8; ++kk){                                        \
            int ra = ((RO) + lr*512 + kk*64 + lg*16) ^ (lr << 4);              \
            short8 Bf = __builtin_bit_cast(short8, *(const uint4*)(Hb + ra));  \
            bc0 = __builtin_amdgcn_mfma_f32_16x16x32_f16(A0[kk], Bf, bc0, 0,0,0);\
            bc1 = __builtin_amdgcn_mfma_f32_16x16x32_f16(A1[kk], Bf, bc1, 0,0,0);\
        }                                                                      \
        f32x4 u0n = *(const f32x4*)(proj + tok2*256 + hd0);                    \
        f32x4 u1n = *(const f32x4*)(proj + tok2*256 + hd1);                    \
        float hn0[4], hn1[4];                                                  \
        _Pragma("unroll")                                                      \
        for (int q = 0; q < 4; ++q){                                           \
            float p0 = ac0[q] + bc0[q];                                        \
            float e0 = __builtin_amdgcn_exp2f(p0 * 2.8853900817779268f);       \
            float r0 = __builtin_amdgcn_rcpf(e0 + 1.f);                        \
            hn0[q] = fmaf(0.7f, hp0[q], fmaf(-0.6f, r0, 0.3f));                \
            hp0[q] = hn0[q];                                                   \
            float p1 = ac1[q] + bc1[q];                                        \
            float e1 = __builtin_amdgcn_exp2f(p1 * 2.8853900817779268f);       \
            float r1 = __builtin_amdgcn_rcpf(e1 + 1.f);                        \
            hn1[q] = fmaf(0.7f, hp1[q], fmaf(-0.6f, r1, 0.3f));                \
            hp1[q] = hn1[q];                                                   \
        }                                                                      \
        uint2 pk0, pk1;                                                        \
        pk0.x = __builtin_bit_cast(uint, __builtin_amdgcn_cvt_pkrtz(hn0[0], hn0[1])); \
        pk0.y = __builtin_bit_cast(uint, __builtin_amdgcn_cvt_pkrtz(hn0[2], hn0[3])); \
        pk1.x = __builtin_bit_cast(uint, __builtin_amdgcn_cvt_pkrtz(hn1[0], hn1[1])); \
        pk1.y = __builtin_bit_cast(uint, __builtin_amdgcn_cvt_pkrtz(hn1[2], hn1[3])); \
        int wa0 = ((WO) + lr*512 + hd0*2) ^ (lr << 4);                         \
        int wa1 = ((WO) + lr*512 + hd1*2) ^ (lr << 4);                         \
        *(uint2*)(Hb + wa0) = pk0;                                             \
        *(uint2*)(Hb + wa1) = pk1;                                             \
        if ((T) >= tw){                                                        \
            *(uint2*)(hsrow + (size_t)(T)*256 + hd0) = pk0;                    \
            *(uint2*)(hsrow + (size_t)(T)*256 + hd1) = pk1;                    \
        }                                                                      \
        u0 = u0n; u1 = u1n; tok2 = tok3;                                       \
        asm volatile("s_waitcnt lgkmcnt(0)\n\ts_barrier" ::: "memory");        \
    }

    for (int t = t0; t < t1; t += 2){
        STEP(t,   0,    8192);
        STEP(t+1, 8192, 0);
    }
#undef STEP
}

// ======== readout: WEIGHTS-STATIONARY 3-kernel split (r14-18 lesson) ======
// Each weight matrix (128 KB) fits LDS entirely: stage ONCE per block, then
// loop over row-tiles with no staging barriers. Activations processed
// IN-PLACE in the hs buffer (row i out depends only on row i in; each wave
// reads its own rows before writing them) -> zero extra workspace, region
// stays L3-resident. 256 blocks (1/CU), 8 waves.

// ---- k_g1: A1 = gelu(hs @ W1.T + b1); fp16 in, bf16 out, in-place --------
// wave owns 4 m-tiles (wfrag 1-read:4-MFMA), all 16 n-tiles; 2 iters x 512 rows.
__global__ __launch_bounds__(512) void k_g1(ushort* act,
        const ushort* __restrict__ W1h, const float* __restrict__ b1){
    __shared__ __align__(16) char w_lds[131072];   // full 256x256 fp16
    const int tid = threadIdx.x, wid = tid >> 6;
    const int lane = tid & 63, lr = lane & 15, lg = lane >> 4;
    #pragma unroll
    for (int i = 0; i < 16; ++i){
        int off = (i*512 + tid) * 16;
        uint4 v = *(const uint4*)((const char*)W1h + off);
        int row = off >> 9;
        *(uint4*)(w_lds + (off ^ ((row & 7) << 4))) = v;
    }
    __syncthreads();
    auto wfrag = [&](int nt, int k0) -> short8 {
        int row  = nt*16 + lr;
        int addr = (row << 9) + k0*64 + lg*16;
        addr ^= (row & 7) << 4;
        return __builtin_bit_cast(short8, *(const uint4*)(w_lds + addr));
    };
    for (int it = 0; it < 2; ++it){
        const size_t mb = (size_t)blockIdx.x*1024 + it*512 + wid*64;
        short8 hb[4][8];
        #pragma unroll
        for (int j = 0; j < 4; ++j){
            const char* p = (const char*)(act + (mb + j*16 + lr)*256) + lg*16;
            #pragma unroll
            for (int k0 = 0; k0 < 8; ++k0)
                hb[j][k0] = __builtin_bit_cast(short8, *(const uint4*)(p + k0*64));
        }
        #pragma unroll
        for (int nt = 0; nt < 16; ++nt){
            int eb = nt*16;
            float4 bi = *(const float4*)(b1 + eb + lg*4);
            f32x4 acc[4];
            #pragma unroll
            for (int j = 0; j < 4; ++j) acc[j] = f32x4{bi.x, bi.y, bi.z, bi.w};
            #pragma unroll
            for (int k0 = 0; k0 < 8; ++k0){
                short8 wf = wfrag(nt, k0);
                #pragma unroll
                for (int j = 0; j < 4; ++j)
                    acc[j] = __builtin_amdgcn_mfma_f32_16x16x32_f16(wf, hb[j][k0], acc[j], 0,0,0);
            }
            #pragma unroll
            for (int j = 0; j < 4; ++j){
                ushort4 g;
                #pragma unroll
                for (int q = 0; q < 4; ++q){
                    float x = acc[j][q];
                    ((ushort*)&g)[q] = f2bf(0.5f*x*(1.f + erff(x*0.70710678118654752440f)));
                }
                *(ushort4*)(act + (mb + j*16 + lr)*256 + eb + lg*4) = g;
            }
        }
    }
}

// ---- k_g2: y = LN(A1 @ W2.T + b2) * gamma + beta; bf16 in/out, in-place --
// wave = (mg 0..3, ng 0..1): 2 m-tiles, half the n-tiles (LN accumulators
// cap m-tiles at 2). 8 iters x 128 rows; 2 barriers/iter (LN exchange only).
__global__ __launch_bounds__(512) void k_g2(ushort* act,
        const ushort* __restrict__ W2b, const float* __restrict__ b2,
        const float* __restrict__ gamma, const float* __restrict__ beta){
    __shared__ __align__(16) char w_lds[131072];
    __shared__ __align__(16) float4 ln_lds[8][16];
    const int tid = threadIdx.x, wid = tid >> 6;
    const int mg = wid >> 1, ng = wid & 1;
    const int lane = tid & 63, lr = lane & 15, lg = lane >> 4;
    #pragma unroll
    for (int i = 0; i < 16; ++i){
        int off = (i*512 + tid) * 16;
        uint4 v = *(const uint4*)((const char*)W2b + off);
        int row = off >> 9;
        *(uint4*)(w_lds + (off ^ ((row & 7) << 4))) = v;
    }
    __syncthreads();
    auto wfrag = [&](int nt, int k0) -> short8 {
        int row  = nt*16 + lr;
        int addr = (row << 9) + k0*64 + lg*16;
        addr ^= (row & 7) << 4;
        return __builtin_bit_cast(short8, *(const uint4*)(w_lds + addr));
    };
    for (int it = 0; it < 8; ++it){
        const size_t m0 = (size_t)blockIdx.x*1024 + it*128;
        const int ml0 = mg*32 + lr, ml1 = ml0 + 16;
        short8 ab0[8], ab1[8];
        {
            const char* p0 = (const char*)(act + (m0 + ml0)*256) + lg*16;
            const char* p1 = (const char*)(act + (m0 + ml1)*256) + lg*16;
            #pragma unroll
            for (int k0 = 0; k0 < 8; ++k0){
                ab0[k0] = __builtin_bit_cast(short8, *(const uint4*)(p0 + k0*64));
                ab1[k0] = __builtin_bit_cast(short8, *(const uint4*)(p1 + k0*64));
            }
        }
        f32x4 o0[8], o1[8];
        #pragma unroll
        for (int n = 0; n < 8; ++n){
            int nt = ng*8 + n;
            int eb = nt*16;
            float4 bi = *(const float4*)(b2 + eb + lg*4);
            f32x4 a0 = {bi.x, bi.y, bi.z, bi.w};
            f32x4 a1 = a0;
            #pragma unroll
            for (int k0 = 0; k0 < 8; ++k0){
                short8 wf = wfrag(nt, k0);
                a0 = __builtin_amdgcn_mfma_f32_16x16x32_bf16(wf, ab0[k0], a0, 0,0,0);
                a1 = __builtin_amdgcn_mfma_f32_16x16x32_bf16(wf, ab1[k0], a1, 0,0,0);
            }
            o0[n] = a0; o1[n] = a1;
        }
        float s0 = 0.f, q0 = 0.f, s1 = 0.f, q1 = 0.f;
        #pragma unroll
        for (int n = 0; n < 8; ++n){
            #pragma unroll
            for (int q = 0; q < 4; ++q){
                float x = o0[n][q]; s0 += x; q0 += x*x;
                float y = o1[n][q]; s1 += y; q1 += y*y;
            }
        }
        s0 += __shfl_xor(s0, 16); q0 += __shfl_xor(q0, 16);
        s0 += __shfl_xor(s0, 32); q0 += __shfl_xor(q0, 32);
        s1 += __shfl_xor(s1, 16); q1 += __shfl_xor(q1, 16);
        s1 += __shfl_xor(s1, 32); q1 += __shfl_xor(q1, 32);
        if (lg == 0) ln_lds[wid][lr] = float4{s0, q0, s1, q1};
        __syncthreads();
        float4 pp = ln_lds[wid ^ 1][lr];
        s0 += pp.x; q0 += pp.y; s1 += pp.z; q1 += pp.w;
        float mu0   = s0 * (1.f/256.f);
        float var0  = q0 * (1.f/256.f) - mu0*mu0;
        float rstd0 = rsqrtf(var0 + 1e-5f);
        float mu1   = s1 * (1.f/256.f);
        float var1  = q1 * (1.f/256.f) - mu1*mu1;
        float rstd1 = rsqrtf(var1 + 1e-5f);
        #pragma unroll
        for (int n = 0; n < 8; ++n){
            int ecol = (ng*8 + n)*16 + lg*4;
            float4 g4 = *(const float4*)(gamma + ecol);
            float4 t4 = *(const float4*)(beta + ecol);
            ushort4 y0, y1;
            #pragma unroll
            for (int q = 0; q < 4; ++q){
                float gq = ((const float*)&g4)[q], tq = ((const float*)&t4)[q];
                ((ushort*)&y0)[q] = f2bf((o0[n][q]-mu0)*rstd0*gq + tq);
                ((ushort*)&y1)[q] = f2bf((o1[n][q]-mu1)*rstd1*gq + tq);
            }
            *(ushort4*)(act + (m0 + ml0)*256 + ecol) = y0;
            *(ushort4*)(act + (m0 + ml1)*256 + ecol) = y1;
        }
        __syncthreads();   // protect ln_lds reuse next iter
    }
}

// ---- k_g3: logits = y @ embed.T; bf16 in, fp32 out (r14-verified stores) -
// wave owns 4 m-tiles, all 16 n-tiles; 2 iters x 512 rows; no loop barriers.
__global__ __launch_bounds__(512) void k_g3(const ushort* act,
        const ushort* __restrict__ Eb, float* __restrict__ out){
    __shared__ __align__(16) char w_lds[131072];
    const int tid = threadIdx.x, wid = tid >> 6;
    const int lane = tid & 63, lr = lane & 15, lg = lane >> 4;
    #pragma unroll
    for (int i = 0; i < 16; ++i){
        int off = (i*512 + tid) * 16;
        uint4 v = *(const uint4*)((const char*)Eb + off);
        int row = off >> 9;
        *(uint4*)(w_lds + (off ^ ((row & 7) << 4))) = v;
    }
    __syncthreads();
    auto wfrag = [&](int nt, int k0) -> short8 {
        int row  = nt*16 + lr;
        int addr = (row << 9) + k0*64 + lg*16;
        addr ^= (row & 7) << 4;
        return __builtin_bit_cast(short8, *(const uint4*)(w_lds + addr));
    };
    for (int it = 0; it < 2; ++it){
        const size_t mb = (size_t)blockIdx.x*1024 + it*512 + wid*64;
        short8 yb[4][8];
        #pragma unroll
        for (int j = 0; j < 4; ++j){
            const char* p = (const char*)(act + (mb + j*16 + lr)*256) + lg*16;
            #pragma unroll
            for (int k0 = 0; k0 < 8; ++k0)
                yb[j][k0] = __builtin_bit_cast(short8, *(const uint4*)(p + k0*64));
        }
        #pragma unroll
        for (int nt = 0; nt < 16; ++nt){
            f32x4 acc[4];
            #pragma unroll
            for (int j = 0; j < 4; ++j) acc[j] = f32x4{0.f,0.f,0.f,0.f};
            #pragma unroll
            for (int k0 = 0; k0 < 8; ++k0){
                short8 wf = wfrag(nt, k0);
                #pragma unroll
                for (int j = 0; j < 4; ++j)
                    acc[j] = __builtin_amdgcn_mfma_f32_16x16x32_bf16(yb[j][k0], wf, acc[j], 0,0,0);
            }
            int v = nt*16 + lr;
            #pragma unroll
            for (int j = 0; j < 4; ++j){
                float* op = out + (mb + j*16 + lg*4)*256 + v;
                op[0]   = acc[j][0];
                op[256] = acc[j][1];
                op[512] = acc[j][2];
                op[768] = acc[j][3];
            }
        }
    }
}

// --------------------------------------------------------------------------
extern "C" void kernel_launch(void* const* d_in, const int* in_sizes, int n_in,
                              void* d_out, int out_size, void* d_ws, size_t ws_size,
                              hipStream_t stream){
    const int*   idx   = (const int*)d_in[0];
    const float* embed = (const float*)d_in[1];
    const float* W_in  = (const float*)d_in[2];
    const float* W     = (const float*)d_in[3];
    const float* W1    = (const float*)d_in[4];
    const float* b1    = (const float*)d_in[5];
    const float* W2    = (const float*)d_in[6];
    const float* b2    = (const float*)d_in[7];
    const float* gamma = (const float*)d_in[8];
    const float* beta  = (const float*)d_in[9];

    char* ws = (char*)d_ws;
    float*  proj  = (float*)ws;                   // 256 KB fp32
    ushort* W1h   = (ushort*)(ws + 262144);       // 128 KB fp16
    ushort* W2b   = (ushort*)(ws + 393216);       // 128 KB bf16
    ushort* Eb    = (ushort*)(ws + 524288);       // 128 KB bf16
    ushort* Wh    = (ushort*)(ws + 655360);       // 128 KB fp16 W
    ushort* act   = (ushort*)(ws + 1048576);      // 134.2 MB [B*T,256]: hs->A1->y in place
    if (ws_size < (size_t)135266304) return;      // ws too small -> recognizable absmax fail

    k_conv <<<256, 256, 0, stream>>>(W1, W2, embed, W, W1h, W2b, Eb, Wh);
    k_proj <<<256, 256, 0, stream>>>(embed, W_in, proj);
    k_recur<<<256, 512, 0, stream>>>(idx, Wh, proj, act);
    k_g1   <<<256, 512, 0, stream>>>(act, W1h, b1);
    k_g2   <<<256, 512, 0, stream>>>(act, W2b, b2, gamma, beta);
    k_g3   <<<256, 512, 0, stream>>>(act, Eb, (float*)d_out);
}

// Round 21
// 645.127 us; speedup vs baseline: 1.1502x; 1.1502x over previous
//
#include <hip/hip_runtime.h>
#include <cstdint>

typedef __attribute__((ext_vector_type(8))) short short8;
typedef __attribute__((ext_vector_type(4))) float f32x4;

__device__ __forceinline__ ushort f2bf(float x){
    uint32_t u = __float_as_uint(x);
    u = (u + 0x7FFFu + ((u >> 16) & 1u)) >> 16;
    return (ushort)u;
}
__device__ __forceinline__ ushort f2h(float x){
    _Float16 h = (_Float16)x;
    return __builtin_bit_cast(ushort, h);
}

// ---- kernel 1: weight conversion (fp16 W, W1, W2; bf16 embed) ------------
__global__ void k_conv(const float* __restrict__ W1, const float* __restrict__ W2,
                       const float* __restrict__ Emb, const float* __restrict__ W,
                       ushort* __restrict__ W1h, ushort* __restrict__ W2h,
                       ushort* __restrict__ Eb, ushort* __restrict__ Wh){
    int i = blockIdx.x * 256 + threadIdx.x;   // grid 256 -> 65536
    W1h[i] = f2h(W1[i]);
    W2h[i] = f2h(W2[i]);
    Eb[i]  = f2bf(Emb[i]);
    Wh[i]  = f2h(W[i]);
}

// -------- kernel 2: proj[v][h] = sum_e embed[v,e]*W_in[h,e]  (fp32) -------
__global__ void k_proj(const float* __restrict__ emb, const float* __restrict__ Win,
                       float* __restrict__ proj){
    __shared__ __align__(16) float se[256];
    int v = blockIdx.x, h = threadIdx.x;
    se[h] = emb[v*256 + h];
    __syncthreads();
    const float* wr = Win + h*256;
    float a0=0.f,a1=0.f,a2=0.f,a3=0.f;
    #pragma unroll
    for (int e = 0; e < 256; e += 4){
        float4 w = *(const float4*)(wr + e);
        a0 = fmaf(w.x, se[e+0], a0);
        a1 = fmaf(w.y, se[e+1], a1);
        a2 = fmaf(w.z, se[e+2], a2);
        a3 = fmaf(w.w, se[e+3], a3);
    }
    proj[v*256 + h] = (a0+a1)+(a2+a3);
}

// ---- kernel 3: ESN recurrence + FUSED GEMM1, fp16, MFMA ------------------
// 256 blocks = (segment s in [0,32)) x (batch group pg in [0,8)), 1 block/CU.
// warmup=128 HW-verified. Critical path 192(+1) steps.
// GEMM1 (z1 = h @ W1^T + b1) reuses the H_t B-fragments in the recurrence's
// idle MFMA slots. TIME ALIGNMENT (r20 bug): at STEP(T) the H buffer holds
// h_{T-1}, so the GEMM1 result is z1[T-1] -> store at (T)-1 when T > tw,
// plus one epilogue STEP(t1) for the final row.
__global__ __launch_bounds__(512, 2) void k_recur(const int* __restrict__ idx,
        const ushort* Wh, const ushort* W1h, const float* __restrict__ b1,
        const float* proj, ushort* z1){
    __shared__ __align__(16) char Hl[2][8192];   // fp16 H[16][256], dbuf, swizzled
    const int tid  = threadIdx.x;
    const int wid  = tid >> 6;
    const int lane = tid & 63;
    const int lr   = lane & 15;        // batch col / A-row-in-tile
    const int lg   = lane >> 4;
    const int seg  = blockIdx.x >> 3;  // time segment 0..31
    const int pg   = blockIdx.x & 7;   // batch group 0..7
    const int t0   = (64*seg - 128 > 0) ? (64*seg - 128) : 0;
    const int t1   = 64*seg + 64;
    const int tw   = 64*seg;           // first written step

    // A-frags: W rows (recurrence) and W1 rows (fused GEMM1) for tiles
    // n0=2*wid, n1=2*wid+1 (fp16, 32 frags = 128 VGPR)
    short8 A0[8], A1[8], B0[8], B1[8];
    {
        const char* wb = (const char*)Wh  + (32*wid + lr)*512 + lg*16;
        const char* vb = (const char*)W1h + (32*wid + lr)*512 + lg*16;
        #pragma unroll
        for (int kk = 0; kk < 8; ++kk){
            A0[kk] = __builtin_bit_cast(short8, *(const uint4*)(wb + kk*64));
            A1[kk] = __builtin_bit_cast(short8, *(const uint4*)(wb + 16*512 + kk*64));
            B0[kk] = __builtin_bit_cast(short8, *(const uint4*)(vb + kk*64));
            B1[kk] = __builtin_bit_cast(short8, *(const uint4*)(vb + 16*512 + kk*64));
        }
    }

    char* Hb = &Hl[0][0];
    *(uint4*)(Hb + tid*16) = uint4{0,0,0,0};     // zero buffer 0 (8 KB)
    __syncthreads();

    const int mybat = pg*16 + lr;
    const int64_t idxbase = (int64_t)mybat * 2048;
    ushort* zrow = z1 + (size_t)mybat * 2048 * 256;
    const int hd0 = 32*wid + lg*4;               // tile0 quad base dim
    const int hd1 = hd0 + 16;

    float hp0[4] = {0.f,0.f,0.f,0.f}, hp1[4] = {0.f,0.f,0.f,0.f};
    const f32x4 bi0 = *(const f32x4*)(b1 + hd0);
    const f32x4 bi1 = *(const f32x4*)(b1 + hd1);

    int tok  = idx[idxbase + t0];
    int tok2 = idx[idxbase + ((t0+1 < 2048) ? t0+1 : 2047)];
    f32x4 u0 = *(const f32x4*)(proj + tok*256 + hd0);
    f32x4 u1 = *(const f32x4*)(proj + tok*256 + hd1);

#define STEP(T, RO, WO)                                                        \
    {                                                                          \
        int tok3 = idx[idxbase + (((T)+2 < 2048) ? (T)+2 : 2047)];             \
        f32x4 ac0 = u0, ac1 = u1;   /* C-init = input projection */            \
        f32x4 bc0 = {0.f,0.f,0.f,0.f}, bc1 = {0.f,0.f,0.f,0.f};                \
        f32x4 g0 = bi0, g1 = bi1;   /* GEMM1 C-init = b1 */                    \
        _Pragma("unroll")                                                      \
        for (int kk = 0; kk < 4; ++kk){                                        \
            int ra = ((RO) + lr*512 + kk*64 + lg*16) ^ (lr << 4);              \
            short8 Bf = __builtin_bit_cast(short8, *(const uint4*)(Hb + ra));  \
            ac0 = __builtin_amdgcn_mfma_f32_16x16x32_f16(A0[kk], Bf, ac0, 0,0,0);\
            ac1 = __builtin_amdgcn_mfma_f32_16x16x32_f16(A1[kk], Bf, ac1, 0,0,0);\
            g0  = __builtin_amdgcn_mfma_f32_16x16x32_f16(B0[kk], Bf, g0, 0,0,0);\
            g1  = __builtin_amdgcn_mfma_f32_16x16x32_f16(B1[kk], Bf, g1, 0,0,0);\
        }                                                                      \
        _Pragma("unroll")                                                      \
        for (int kk = 4; kk < 8; ++kk){                                        \
            int ra = ((RO) + lr*512 + kk*64 + lg*16) ^ (lr << 4);              \
            short8 Bf = __builtin_bit_cast(short8, *(const uint4*)(Hb + ra));  \
            bc0 = __builtin_amdgcn_mfma_f32_16x16x32_f16(A0[kk], Bf, bc0, 0,0,0);\
            bc1 = __builtin_amdgcn_mfma_f32_16x16x32_f16(A1[kk], Bf, bc1, 0,0,0);\
            g0  = __builtin_amdgcn_mfma_f32_16x16x32_f16(B0[kk], Bf, g0, 0,0,0);\
            g1  = __builtin_amdgcn_mfma_f32_16x16x32_f16(B1[kk], Bf, g1, 0,0,0);\
        }                                                                      \
        if ((T) > tw){   /* z1[T-1] = W1 @ h_{T-1} + b1 (time-aligned) */      \
            uint2 zk0, zk1;                                                    \
            zk0.x = __builtin_bit_cast(uint, __builtin_amdgcn_cvt_pkrtz(g0[0], g0[1])); \
            zk0.y = __builtin_bit_cast(uint, __builtin_amdgcn_cvt_pkrtz(g0[2], g0[3])); \
            zk1.x = __builtin_bit_cast(uint, __builtin_amdgcn_cvt_pkrtz(g1[0], g1[1])); \
            zk1.y = __builtin_bit_cast(uint, __builtin_amdgcn_cvt_pkrtz(g1[2], g1[3])); \
            *(uint2*)(zrow + (size_t)((T)-1)*256 + hd0) = zk0;                 \
            *(uint2*)(zrow + (size_t)((T)-1)*256 + hd1) = zk1;                 \
        }                                                                      \
        f32x4 u0n = *(const f32x4*)(proj + tok2*256 + hd0);                    \
        f32x4 u1n = *(const f32x4*)(proj + tok2*256 + hd1);                    \
        float hn0[4], hn1[4];                                                  \
        _Pragma("unroll")                                                      \
        for (int q = 0; q < 4; ++q){                                           \
            float p0 = ac0[q] + bc0[q];                                        \
            float e0 = __builtin_amdgcn_exp2f(p0 * 2.8853900817779268f);       \
            float r0 = __builtin_amdgcn_rcpf(e0 + 1.f);                        \
            hn0[q] = fmaf(0.7f, hp0[q], fmaf(-0.6f, r0, 0.3f));                \
            hp0[q] = hn0[q];                                                   \
            float p1 = ac1[q] + bc1[q];                                        \
            float e1 = __builtin_amdgcn_exp2f(p1 * 2.8853900817779268f);       \
            float r1 = __builtin_amdgcn_rcpf(e1 + 1.f);                        \
            hn1[q] = fmaf(0.7f, hp1[q], fmaf(-0.6f, r1, 0.3f));                \
            hp1[q] = hn1[q];                                                   \
        }                                                                      \
        uint2 pk0, pk1;                                                        \
        pk0.x = __builtin_bit_cast(uint, __builtin_amdgcn_cvt_pkrtz(hn0[0], hn0[1])); \
        pk0.y = __builtin_bit_cast(uint, __builtin_amdgcn_cvt_pkrtz(hn0[2], hn0[3])); \
        pk1.x = __builtin_bit_cast(uint, __builtin_amdgcn_cvt_pkrtz(hn1[0], hn1[1])); \
        pk1.y = __builtin_bit_cast(uint, __builtin_amdgcn_cvt_pkrtz(hn1[2], hn1[3])); \
        int wa0 = ((WO) + lr*512 + hd0*2) ^ (lr << 4);                         \
        int wa1 = ((WO) + lr*512 + hd1*2) ^ (lr << 4);                         \
        *(uint2*)(Hb + wa0) = pk0;                                             \
        *(uint2*)(Hb + wa1) = pk1;                                             \
        u0 = u0n; u1 = u1n; tok2 = tok3;                                       \
        asm volatile("s_waitcnt lgkmcnt(0)\n\ts_barrier" ::: "memory");        \
    }

    for (int t = t0; t < t1; t += 2){
        STEP(t,   0,    8192);
        STEP(t+1, 8192, 0);
    }
    STEP(t1, 0, 8192);   // epilogue: emits z1[t1-1]
#undef STEP
}

// ---- kernel 4: readout tail: gelu(z1) @ W2.T + b2 -> LN -> @ embed.T -----
// r14 structure minus GEMM1: 2048 blocks x 128 rows, 8 waves = (mg x ng).
// ab frags come straight from global z1 with gelu applied on load (erff,
// exact). GEMM2 fp16; LN + bf16 GEMM3 verbatim from r14 (HW-verified).
__global__ __launch_bounds__(512) void k_readout(
        const ushort* __restrict__ z1,
        const ushort* __restrict__ W2h, const ushort* __restrict__ Eb,
        const float* __restrict__ b2,
        const float* __restrict__ gamma, const float* __restrict__ beta,
        float* __restrict__ out){
    __shared__ __align__(16) char w_lds[65536];   // staged weight half
    __shared__ __align__(16) char a_lds[65536];   // y tile: 128 x 256 x 2B
    __shared__ __align__(16) float4 ln_lds[8][16];

    const int tid  = threadIdx.x;
    const int wid  = tid >> 6;
    const int mg   = wid >> 1;
    const int ng   = wid & 1;
    const int lane = tid & 63;
    const int lr   = lane & 15;
    const int lg   = lane >> 4;
    const size_t m0 = (size_t)blockIdx.x * 128;
    const int ml0  = mg*32 + lr;
    const int ml1  = ml0 + 16;

    auto stage = [&](const ushort* src){
        #pragma unroll
        for (int i = 0; i < 8; ++i){
            int off = (i*512 + tid) * 16;
            uint4 v = *(const uint4*)((const char*)src + off);
            int row = off >> 9;
            *(uint4*)(w_lds + (off ^ ((row & 7) << 4))) = v;
        }
    };
    auto wfrag = [&](int n, int k0) -> short8 {
        int row  = n*16 + lr;
        int addr = (row << 9) + k0*64 + lg*16;
        addr ^= (row & 7) << 4;
        return __builtin_bit_cast(short8, *(const uint4*)(w_lds + addr));
    };
    auto afrag = [&](int ml, int k0) -> short8 {
        int addr = (ml << 9) + k0*64 + lg*16;
        addr ^= (ml & 7) << 4;
        return __builtin_bit_cast(short8, *(const uint4*)(a_lds + addr));
    };
    auto awrite = [&](int ml, int ecol, f32x4 v){
        ushort4 pk;
        pk.x = f2bf(v[0]); pk.y = f2bf(v[1]); pk.z = f2bf(v[2]); pk.w = f2bf(v[3]);
        int addr = (ml << 9) + ecol*2;
        addr ^= (ml & 7) << 4;
        *(ushort4*)(a_lds + addr) = pk;
    };
    // gelu on a packed fp16 frag (8 values), exact erf, repack fp16
    auto gelu8 = [&](short8 z) -> short8 {
        short8 r;
        #pragma unroll
        for (int q = 0; q < 4; ++q){
            float xa = (float)__builtin_bit_cast(_Float16, (ushort)z[2*q]);
            float xb = (float)__builtin_bit_cast(_Float16, (ushort)z[2*q+1]);
            float ga = 0.5f*xa*(1.f + erff(xa*0.70710678118654752440f));
            float gb = 0.5f*xb*(1.f + erff(xb*0.70710678118654752440f));
            uint p = __builtin_bit_cast(uint, __builtin_amdgcn_cvt_pkrtz(ga, gb));
            r[2*q]   = (short)(p & 0xffff);
            r[2*q+1] = (short)(p >> 16);
        }
        return r;
    };

    // ---- load z1 frags for both m-tiles, gelu on the fly ----
    short8 ab0[8], ab1[8];
    {
        const char* p0 = (const char*)(z1 + (m0 + ml0)*256) + lg*16;
        const char* p1 = (const char*)(z1 + (m0 + ml1)*256) + lg*16;
        #pragma unroll
        for (int k0 = 0; k0 < 8; ++k0){
            ab0[k0] = gelu8(__builtin_bit_cast(short8, *(const uint4*)(p0 + k0*64)));
            ab1[k0] = gelu8(__builtin_bit_cast(short8, *(const uint4*)(p1 + k0*64)));
        }
    }

    // ================= GEMM2 (fp16): o = A1 @ W2.T + b2 =================
    f32x4 oacc0[8], oacc1[8];
    #pragma unroll
    for (int h = 0; h < 2; ++h){
        __syncthreads();
        stage(W2h + h*128*256);
        __syncthreads();
        #pragma unroll
        for (int n = 0; n < 4; ++n){
            int nt = 4*ng + n;
            int eb = h*128 + nt*16;
            float4 bi = *(const float4*)(b2 + eb + lg*4);
            f32x4 acc0 = {bi.x, bi.y, bi.z, bi.w};
            f32x4 acc1 = acc0;
            #pragma unroll
            for (int k0 = 0; k0 < 8; ++k0){
                short8 wf = wfrag(nt, k0);
                acc0 = __builtin_amdgcn_mfma_f32_16x16x32_f16(wf, ab0[k0], acc0, 0,0,0);
                acc1 = __builtin_amdgcn_mfma_f32_16x16x32_f16(wf, ab1[k0], acc1, 0,0,0);
            }
            oacc0[h*4+n] = acc0;
            oacc1[h*4+n] = acc1;
        }
    }

    // ====== LayerNorm over e2: in-wave shfl + cross-wave (ng pair) LDS ======
    {
        float s0 = 0.f, q0 = 0.f, s1 = 0.f, q1 = 0.f;
        #pragma unroll
        for (int i = 0; i < 8; ++i){
            #pragma unroll
            for (int q = 0; q < 4; ++q){
                float x = oacc0[i][q]; s0 += x; q0 += x*x;
                float y = oacc1[i][q]; s1 += y; q1 += y*y;
            }
        }
        s0 += __shfl_xor(s0, 16); q0 += __shfl_xor(q0, 16);
        s0 += __shfl_xor(s0, 32); q0 += __shfl_xor(q0, 32);
        s1 += __shfl_xor(s1, 16); q1 += __shfl_xor(q1, 16);
        s1 += __shfl_xor(s1, 32); q1 += __shfl_xor(q1, 32);
        __syncthreads();                     // all waves done reading w_lds h1
        if (lg == 0) ln_lds[wid][lr] = float4{s0, q0, s1, q1};
        __syncthreads();
        float4 pp = ln_lds[wid ^ 1][lr];
        s0 += pp.x; q0 += pp.y; s1 += pp.z; q1 += pp.w;
        float mu0   = s0 * (1.f/256.f);
        float var0  = q0 * (1.f/256.f) - mu0*mu0;
        float rstd0 = rsqrtf(var0 + 1e-5f);
        float mu1   = s1 * (1.f/256.f);
        float var1  = q1 * (1.f/256.f) - mu1*mu1;
        float rstd1 = rsqrtf(var1 + 1e-5f);
        #pragma unroll
        for (int i = 0; i < 8; ++i){
            int h = i >> 2, n = i & 3;
            int ecol = h*128 + (4*ng + n)*16 + lg*4;
            float4 g4 = *(const float4*)(gamma + ecol);
            float4 t4 = *(const float4*)(beta + ecol);
            f32x4 y0, y1;
            y0[0] = (oacc0[i][0]-mu0)*rstd0*g4.x + t4.x;
            y0[1] = (oacc0[i][1]-mu0)*rstd0*g4.y + t4.y;
            y0[2] = (oacc0[i][2]-mu0)*rstd0*g4.z + t4.z;
            y0[3] = (oacc0[i][3]-mu0)*rstd0*g4.w + t4.w;
            y1[0] = (oacc1[i][0]-mu1)*rstd1*g4.x + t4.x;
            y1[1] = (oacc1[i][1]-mu1)*rstd1*g4.y + t4.y;
            y1[2] = (oacc1[i][2]-mu1)*rstd1*g4.z + t4.z;
            y1[3] = (oacc1[i][3]-mu1)*rstd1*g4.w + t4.w;
            awrite(ml0, ecol, y0);
            awrite(ml1, ecol, y1);
        }
    }

    // ================= GEMM3 (bf16): logits = y @ embed.T =================
    __syncthreads();
    short8 yb0[8], yb1[8];
    #pragma unroll
    for (int k0 = 0; k0 < 8; ++k0){ yb0[k0] = afrag(ml0, k0); yb1[k0] = afrag(ml1, k0); }
    #pragma unroll
    for (int h = 0; h < 2; ++h){
        __syncthreads();
        stage(Eb + h*128*256);
        __syncthreads();
        #pragma unroll
        for (int n = 0; n < 4; ++n){
            int nt = 4*ng + n;
            f32x4 acc0 = {0.f,0.f,0.f,0.f};
            f32x4 acc1 = acc0;
            #pragma unroll
            for (int k0 = 0; k0 < 8; ++k0){
                short8 wf = wfrag(nt, k0);
                acc0 = __builtin_amdgcn_mfma_f32_16x16x32_bf16(yb0[k0], wf, acc0, 0,0,0);
                acc1 = __builtin_amdgcn_mfma_f32_16x16x32_bf16(yb1[k0], wf, acc1, 0,0,0);
            }
            int v = h*128 + nt*16 + lr;
            float* op0 = out + (m0 + mg*32 + lg*4)*256 + v;
            op0[0]   = acc0[0];
            op0[256] = acc0[1];
            op0[512] = acc0[2];
            op0[768] = acc0[3];
            float* op1 = out + (m0 + mg*32 + 16 + lg*4)*256 + v;
            op1[0]   = acc1[0];
            op1[256] = acc1[1];
            op1[512] = acc1[2];
            op1[768] = acc1[3];
        }
    }
}

// --------------------------------------------------------------------------
extern "C" void kernel_launch(void* const* d_in, const int* in_sizes, int n_in,
                              void* d_out, int out_size, void* d_ws, size_t ws_size,
                              hipStream_t stream){
    const int*   idx   = (const int*)d_in[0];
    const float* embed = (const float*)d_in[1];
    const float* W_in  = (const float*)d_in[2];
    const float* W     = (const float*)d_in[3];
    const float* W1    = (const float*)d_in[4];
    const float* b1    = (const float*)d_in[5];
    const float* W2    = (const float*)d_in[6];
    const float* b2    = (const float*)d_in[7];
    const float* gamma = (const float*)d_in[8];
    const float* beta  = (const float*)d_in[9];

    char* ws = (char*)d_ws;
    float*  proj  = (float*)ws;                   // 256 KB fp32
    ushort* W1h   = (ushort*)(ws + 262144);       // 128 KB fp16
    ushort* W2h   = (ushort*)(ws + 393216);       // 128 KB fp16
    ushort* Eb    = (ushort*)(ws + 524288);       // 128 KB bf16
    ushort* Wh    = (ushort*)(ws + 655360);       // 128 KB fp16 W
    ushort* z1    = (ushort*)(ws + 1048576);      // 134.2 MB fp16 [B*T,256] pre-gelu
    if (ws_size < (size_t)135266304) return;      // ws too small -> recognizable absmax fail

    k_conv   <<<256, 256, 0, stream>>>(W1, W2, embed, W, W1h, W2h, Eb, Wh);
    k_proj   <<<256, 256, 0, stream>>>(embed, W_in, proj);
    k_recur  <<<256, 512, 0, stream>>>(idx, Wh, W1h, b1, proj, z1);
    k_readout<<<2048, 512, 0, stream>>>(z1, W2h, Eb, b2, gamma, beta, (float*)d_out);
}

// Round 22
// 386.596 us; speedup vs baseline: 1.9194x; 1.6687x over previous
//
#include <hip/hip_runtime.h>
#include <cstdint>

typedef __attribute__((ext_vector_type(8))) short short8;
typedef __attribute__((ext_vector_type(4))) float f32x4;

__device__ __forceinline__ ushort f2bf(float x){
    uint32_t u = __float_as_uint(x);
    u = (u + 0x7FFFu + ((u >> 16) & 1u)) >> 16;
    return (ushort)u;
}
__device__ __forceinline__ ushort f2h(float x){
    _Float16 h = (_Float16)x;
    return __builtin_bit_cast(ushort, h);
}

// ---- kernel 1: weight conversion (fp16 W, W1, W2; bf16 embed) ------------
__global__ void k_conv(const float* __restrict__ W1, const float* __restrict__ W2,
                       const float* __restrict__ Emb, const float* __restrict__ W,
                       ushort* __restrict__ W1h, ushort* __restrict__ W2h,
                       ushort* __restrict__ Eb, ushort* __restrict__ Wh){
    int i = blockIdx.x * 256 + threadIdx.x;   // grid 256 -> 65536
    W1h[i] = f2h(W1[i]);
    W2h[i] = f2h(W2[i]);
    Eb[i]  = f2bf(Emb[i]);
    Wh[i]  = f2h(W[i]);
}

// -------- kernel 2: proj[v][h] = sum_e embed[v,e]*W_in[h,e]  (fp32) -------
__global__ void k_proj(const float* __restrict__ emb, const float* __restrict__ Win,
                       float* __restrict__ proj){
    __shared__ __align__(16) float se[256];
    int v = blockIdx.x, h = threadIdx.x;
    se[h] = emb[v*256 + h];
    __syncthreads();
    const float* wr = Win + h*256;
    float a0=0.f,a1=0.f,a2=0.f,a3=0.f;
    #pragma unroll
    for (int e = 0; e < 256; e += 4){
        float4 w = *(const float4*)(wr + e);
        a0 = fmaf(w.x, se[e+0], a0);
        a1 = fmaf(w.y, se[e+1], a1);
        a2 = fmaf(w.z, se[e+2], a2);
        a3 = fmaf(w.w, se[e+3], a3);
    }
    proj[v*256 + h] = (a0+a1)+(a2+a3);
}

// ---- kernel 3: ESN recurrence + FUSED GEMM1, fp16, MFMA (r21-verified) ---
// 256 blocks = (segment s in [0,32)) x (batch group pg in [0,8)), 1 block/CU.
// warmup=128 HW-verified. Critical path 192(+1) steps (~145us, r21).
// GEMM1 (z1 = h @ W1^T + b1) reuses the H_t B-fragments in the recurrence's
// idle MFMA slots; at STEP(T) the H buffer holds h_{T-1} so the result is
// stored as z1[T-1] (T > tw), plus one epilogue STEP for the final row.
__global__ __launch_bounds__(512, 2) void k_recur(const int* __restrict__ idx,
        const ushort* Wh, const ushort* W1h, const float* __restrict__ b1,
        const float* proj, ushort* z1){
    __shared__ __align__(16) char Hl[2][8192];   // fp16 H[16][256], dbuf, swizzled
    const int tid  = threadIdx.x;
    const int wid  = tid >> 6;
    const int lane = tid & 63;
    const int lr   = lane & 15;        // batch col / A-row-in-tile
    const int lg   = lane >> 4;
    const int seg  = blockIdx.x >> 3;  // time segment 0..31
    const int pg   = blockIdx.x & 7;   // batch group 0..7
    const int t0   = (64*seg - 128 > 0) ? (64*seg - 128) : 0;
    const int t1   = 64*seg + 64;
    const int tw   = 64*seg;           // first written step

    // A-frags: W rows (recurrence) and W1 rows (fused GEMM1) for tiles
    // n0=2*wid, n1=2*wid+1 (fp16, 32 frags = 128 VGPR)
    short8 A0[8], A1[8], B0[8], B1[8];
    {
        const char* wb = (const char*)Wh  + (32*wid + lr)*512 + lg*16;
        const char* vb = (const char*)W1h + (32*wid + lr)*512 + lg*16;
        #pragma unroll
        for (int kk = 0; kk < 8; ++kk){
            A0[kk] = __builtin_bit_cast(short8, *(const uint4*)(wb + kk*64));
            A1[kk] = __builtin_bit_cast(short8, *(const uint4*)(wb + 16*512 + kk*64));
            B0[kk] = __builtin_bit_cast(short8, *(const uint4*)(vb + kk*64));
            B1[kk] = __builtin_bit_cast(short8, *(const uint4*)(vb + 16*512 + kk*64));
        }
    }

    char* Hb = &Hl[0][0];
    *(uint4*)(Hb + tid*16) = uint4{0,0,0,0};     // zero buffer 0 (8 KB)
    __syncthreads();

    const int mybat = pg*16 + lr;
    const int64_t idxbase = (int64_t)mybat * 2048;
    ushort* zrow = z1 + (size_t)mybat * 2048 * 256;
    const int hd0 = 32*wid + lg*4;               // tile0 quad base dim
    const int hd1 = hd0 + 16;

    float hp0[4] = {0.f,0.f,0.f,0.f}, hp1[4] = {0.f,0.f,0.f,0.f};
    const f32x4 bi0 = *(const f32x4*)(b1 + hd0);
    const f32x4 bi1 = *(const f32x4*)(b1 + hd1);

    int tok  = idx[idxbase + t0];
    int tok2 = idx[idxbase + ((t0+1 < 2048) ? t0+1 : 2047)];
    f32x4 u0 = *(const f32x4*)(proj + tok*256 + hd0);
    f32x4 u1 = *(const f32x4*)(proj + tok*256 + hd1);

#define STEP(T, RO, WO)                                                        \
    {                                                                          \
        int tok3 = idx[idxbase + (((T)+2 < 2048) ? (T)+2 : 2047)];             \
        f32x4 ac0 = u0, ac1 = u1;   /* C-init = input projection */            \
        f32x4 bc0 = {0.f,0.f,0.f,0.f}, bc1 = {0.f,0.f,0.f,0.f};                \
        f32x4 g0 = bi0, g1 = bi1;   /* GEMM1 C-init = b1 */                    \
        _Pragma("unroll")                                                      \
        for (int kk = 0; kk < 4; ++kk){                                        \
            int ra = ((RO) + lr*512 + kk*64 + lg*16) ^ (lr << 4);              \
            short8 Bf = __builtin_bit_cast(short8, *(const uint4*)(Hb + ra));  \
            ac0 = __builtin_amdgcn_mfma_f32_16x16x32_f16(A0[kk], Bf, ac0, 0,0,0);\
            ac1 = __builtin_amdgcn_mfma_f32_16x16x32_f16(A1[kk], Bf, ac1, 0,0,0);\
            g0  = __builtin_amdgcn_mfma_f32_16x16x32_f16(B0[kk], Bf, g0, 0,0,0);\
            g1  = __builtin_amdgcn_mfma_f32_16x16x32_f16(B1[kk], Bf, g1, 0,0,0);\
        }                                                                      \
        _Pragma("unroll")                                                      \
        for (int kk = 4; kk < 8; ++kk){                                        \
            int ra = ((RO) + lr*512 + kk*64 + lg*16) ^ (lr << 4);              \
            short8 Bf = __builtin_bit_cast(short8, *(const uint4*)(Hb + ra));  \
            bc0 = __builtin_amdgcn_mfma_f32_16x16x32_f16(A0[kk], Bf, bc0, 0,0,0);\
            bc1 = __builtin_amdgcn_mfma_f32_16x16x32_f16(A1[kk], Bf, bc1, 0,0,0);\
            g0  = __builtin_amdgcn_mfma_f32_16x16x32_f16(B0[kk], Bf, g0, 0,0,0);\
            g1  = __builtin_amdgcn_mfma_f32_16x16x32_f16(B1[kk], Bf, g1, 0,0,0);\
        }                                                                      \
        if ((T) > tw){   /* z1[T-1] = W1 @ h_{T-1} + b1 (time-aligned) */      \
            uint2 zk0, zk1;                                                    \
            zk0.x = __builtin_bit_cast(uint, __builtin_amdgcn_cvt_pkrtz(g0[0], g0[1])); \
            zk0.y = __builtin_bit_cast(uint, __builtin_amdgcn_cvt_pkrtz(g0[2], g0[3])); \
            zk1.x = __builtin_bit_cast(uint, __builtin_amdgcn_cvt_pkrtz(g1[0], g1[1])); \
            zk1.y = __builtin_bit_cast(uint, __builtin_amdgcn_cvt_pkrtz(g1[2], g1[3])); \
            *(uint2*)(zrow + (size_t)((T)-1)*256 + hd0) = zk0;                 \
            *(uint2*)(zrow + (size_t)((T)-1)*256 + hd1) = zk1;                 \
        }                                                                      \
        f32x4 u0n = *(const f32x4*)(proj + tok2*256 + hd0);                    \
        f32x4 u1n = *(const f32x4*)(proj + tok2*256 + hd1);                    \
        float hn0[4], hn1[4];                                                  \
        _Pragma("unroll")                                                      \
        for (int q = 0; q < 4; ++q){                                           \
            float p0 = ac0[q] + bc0[q];                                        \
            float e0 = __builtin_amdgcn_exp2f(p0 * 2.8853900817779268f);       \
            float r0 = __builtin_amdgcn_rcpf(e0 + 1.f);                        \
            hn0[q] = fmaf(0.7f, hp0[q], fmaf(-0.6f, r0, 0.3f));                \
            hp0[q] = hn0[q];                                                   \
            float p1 = ac1[q] + bc1[q];                                        \
            float e1 = __builtin_amdgcn_exp2f(p1 * 2.8853900817779268f);       \
            float r1 = __builtin_amdgcn_rcpf(e1 + 1.f);                        \
            hn1[q] = fmaf(0.7f, hp1[q], fmaf(-0.6f, r1, 0.3f));                \
            hp1[q] = hn1[q];                                                   \
        }                                                                      \
        uint2 pk0, pk1;                                                        \
        pk0.x = __builtin_bit_cast(uint, __builtin_amdgcn_cvt_pkrtz(hn0[0], hn0[1])); \
        pk0.y = __builtin_bit_cast(uint, __builtin_amdgcn_cvt_pkrtz(hn0[2], hn0[3])); \
        pk1.x = __builtin_bit_cast(uint, __builtin_amdgcn_cvt_pkrtz(hn1[0], hn1[1])); \
        pk1.y = __builtin_bit_cast(uint, __builtin_amdgcn_cvt_pkrtz(hn1[2], hn1[3])); \
        int wa0 = ((WO) + lr*512 + hd0*2) ^ (lr << 4);                         \
        int wa1 = ((WO) + lr*512 + hd1*2) ^ (lr << 4);                         \
        *(uint2*)(Hb + wa0) = pk0;                                             \
        *(uint2*)(Hb + wa1) = pk1;                                             \
        u0 = u0n; u1 = u1n; tok2 = tok3;                                       \
        asm volatile("s_waitcnt lgkmcnt(0)\n\ts_barrier" ::: "memory");        \
    }

    for (int t = t0; t < t1; t += 2){
        STEP(t,   0,    8192);
        STEP(t+1, 8192, 0);
    }
    STEP(t1, 0, 8192);   // epilogue: emits z1[t1-1]
#undef STEP
}

// ---- kernel 4: readout tail: gelu(z1) @ W2.T + b2 -> LN -> @ embed.T -----
// r14 structure minus GEMM1. Phase 0 applies gelu per-fragment with SHORT
// liveness: load 16B of z1 -> gelu 8 vals -> pack fp16 -> store to a_lds
// at the exact address afrag later reads (same thread; no barrier needed).
// r21's reg-resident gelu spilled (WRITE 262->848MB, scratch): fixed here.
// GEMM2 fp16; LN + bf16 GEMM3 verbatim from r14 (HW-verified).
__global__ __launch_bounds__(512) void k_readout(
        const ushort* __restrict__ z1,
        const ushort* __restrict__ W2h, const ushort* __restrict__ Eb,
        const float* __restrict__ b2,
        const float* __restrict__ gamma, const float* __restrict__ beta,
        float* __restrict__ out){
    __shared__ __align__(16) char w_lds[65536];   // staged weight half
    __shared__ __align__(16) char a_lds[65536];   // A1 / y tile: 128 x 256 x 2B
    __shared__ __align__(16) float4 ln_lds[8][16];

    const int tid  = threadIdx.x;
    const int wid  = tid >> 6;
    const int mg   = wid >> 1;
    const int ng   = wid & 1;
    const int lane = tid & 63;
    const int lr   = lane & 15;
    const int lg   = lane >> 4;
    const size_t m0 = (size_t)blockIdx.x * 128;
    const int ml0  = mg*32 + lr;
    const int ml1  = ml0 + 16;

    auto stage = [&](const ushort* src){
        #pragma unroll
        for (int i = 0; i < 8; ++i){
            int off = (i*512 + tid) * 16;
            uint4 v = *(const uint4*)((const char*)src + off);
            int row = off >> 9;
            *(uint4*)(w_lds + (off ^ ((row & 7) << 4))) = v;
        }
    };
    auto wfrag = [&](int n, int k0) -> short8 {
        int row  = n*16 + lr;
        int addr = (row << 9) + k0*64 + lg*16;
        addr ^= (row & 7) << 4;
        return __builtin_bit_cast(short8, *(const uint4*)(w_lds + addr));
    };
    auto afrag = [&](int ml, int k0) -> short8 {
        int addr = (ml << 9) + k0*64 + lg*16;
        addr ^= (ml & 7) << 4;
        return __builtin_bit_cast(short8, *(const uint4*)(a_lds + addr));
    };
    auto awrite = [&](int ml, int ecol, f32x4 v){
        ushort4 pk;
        pk.x = f2bf(v[0]); pk.y = f2bf(v[1]); pk.z = f2bf(v[2]); pk.w = f2bf(v[3]);
        int addr = (ml << 9) + ecol*2;
        addr ^= (ml & 7) << 4;
        *(ushort4*)(a_lds + addr) = pk;
    };
    // gelu on one packed 16B fragment (8 fp16), exact erf, repack fp16
    auto gelupk = [&](uint4 z) -> uint4 {
        uint4 r;
        #pragma unroll
        for (int q = 0; q < 4; ++q){
            uint w = ((const uint*)&z)[q];
            float xa = (float)__builtin_bit_cast(_Float16, (ushort)(w & 0xffffu));
            float xb = (float)__builtin_bit_cast(_Float16, (ushort)(w >> 16));
            float ga = 0.5f*xa*(1.f + erff(xa*0.70710678118654752440f));
            float gb = 0.5f*xb*(1.f + erff(xb*0.70710678118654752440f));
            ((uint*)&r)[q] = __builtin_bit_cast(uint, __builtin_amdgcn_cvt_pkrtz(ga, gb));
        }
        return r;
    };

    // ---- Phase 0: gelu(z1) -> a_lds (fp16), per-frag short liveness ----
    {
        const char* p0 = (const char*)(z1 + (m0 + ml0)*256) + lg*16;
        const char* p1 = (const char*)(z1 + (m0 + ml1)*256) + lg*16;
        #pragma unroll
        for (int k0 = 0; k0 < 8; ++k0){
            uint4 g0 = gelupk(*(const uint4*)(p0 + k0*64));
            int a0 = ((ml0 << 9) + k0*64 + lg*16) ^ ((ml0 & 7) << 4);
            *(uint4*)(a_lds + a0) = g0;
            uint4 g1 = gelupk(*(const uint4*)(p1 + k0*64));
            int a1 = ((ml1 << 9) + k0*64 + lg*16) ^ ((ml1 & 7) << 4);
            *(uint4*)(a_lds + a1) = g1;
        }
    }

    // ================= GEMM2 (fp16): o = A1 @ W2.T + b2 =================
    short8 ab0[8], ab1[8];
    #pragma unroll
    for (int k0 = 0; k0 < 8; ++k0){ ab0[k0] = afrag(ml0, k0); ab1[k0] = afrag(ml1, k0); }
    f32x4 oacc0[8], oacc1[8];
    #pragma unroll
    for (int h = 0; h < 2; ++h){
        __syncthreads();
        stage(W2h + h*128*256);
        __syncthreads();
        #pragma unroll
        for (int n = 0; n < 4; ++n){
            int nt = 4*ng + n;
            int eb = h*128 + nt*16;
            float4 bi = *(const float4*)(b2 + eb + lg*4);
            f32x4 acc0 = {bi.x, bi.y, bi.z, bi.w};
            f32x4 acc1 = acc0;
            #pragma unroll
            for (int k0 = 0; k0 < 8; ++k0){
                short8 wf = wfrag(nt, k0);
                acc0 = __builtin_amdgcn_mfma_f32_16x16x32_f16(wf, ab0[k0], acc0, 0,0,0);
                acc1 = __builtin_amdgcn_mfma_f32_16x16x32_f16(wf, ab1[k0], acc1, 0,0,0);
            }
            oacc0[h*4+n] = acc0;
            oacc1[h*4+n] = acc1;
        }
    }

    // ====== LayerNorm over e2: in-wave shfl + cross-wave (ng pair) LDS ======
    {
        float s0 = 0.f, q0 = 0.f, s1 = 0.f, q1 = 0.f;
        #pragma unroll
        for (int i = 0; i < 8; ++i){
            #pragma unroll
            for (int q = 0; q < 4; ++q){
                float x = oacc0[i][q]; s0 += x; q0 += x*x;
                float y = oacc1[i][q]; s1 += y; q1 += y*y;
            }
        }
        s0 += __shfl_xor(s0, 16); q0 += __shfl_xor(q0, 16);
        s0 += __shfl_xor(s0, 32); q0 += __shfl_xor(q0, 32);
        s1 += __shfl_xor(s1, 16); q1 += __shfl_xor(q1, 16);
        s1 += __shfl_xor(s1, 32); q1 += __shfl_xor(q1, 32);
        __syncthreads();                     // all waves done reading w_lds h1
        if (lg == 0) ln_lds[wid][lr] = float4{s0, q0, s1, q1};
        __syncthreads();
        float4 pp = ln_lds[wid ^ 1][lr];
        s0 += pp.x; q0 += pp.y; s1 += pp.z; q1 += pp.w;
        float mu0   = s0 * (1.f/256.f);
        float var0  = q0 * (1.f/256.f) - mu0*mu0;
        float rstd0 = rsqrtf(var0 + 1e-5f);
        float mu1   = s1 * (1.f/256.f);
        float var1  = q1 * (1.f/256.f) - mu1*mu1;
        float rstd1 = rsqrtf(var1 + 1e-5f);
        #pragma unroll
        for (int i = 0; i < 8; ++i){
            int h = i >> 2, n = i & 3;
            int ecol = h*128 + (4*ng + n)*16 + lg*4;
            float4 g4 = *(const float4*)(gamma + ecol);
            float4 t4 = *(const float4*)(beta + ecol);
            f32x4 y0, y1;
            y0[0] = (oacc0[i][0]-mu0)*rstd0*g4.x + t4.x;
            y0[1] = (oacc0[i][1]-mu0)*rstd0*g4.y + t4.y;
            y0[2] = (oacc0[i][2]-mu0)*rstd0*g4.z + t4.z;
            y0[3] = (oacc0[i][3]-mu0)*rstd0*g4.w + t4.w;
            y1[0] = (oacc1[i][0]-mu1)*rstd1*g4.x + t4.x;
            y1[1] = (oacc1[i][1]-mu1)*rstd1*g4.y + t4.y;
            y1[2] = (oacc1[i][2]-mu1)*rstd1*g4.z + t4.z;
            y1[3] = (oacc1[i][3]-mu1)*rstd1*g4.w + t4.w;
            awrite(ml0, ecol, y0);
            awrite(ml1, ecol, y1);
        }
    }

    // ================= GEMM3 (bf16): logits = y @ embed.T =================
    __syncthreads();
    short8 yb0[8], yb1[8];
    #pragma unroll
    for (int k0 = 0; k0 < 8; ++k0){ yb0[k0] = afrag(ml0, k0); yb1[k0] = afrag(ml1, k0); }
    #pragma unroll
    for (int h = 0; h < 2; ++h){
        __syncthreads();
        stage(Eb + h*128*256);
        __syncthreads();
        #pragma unroll
        for (int n = 0; n < 4; ++n){
            int nt = 4*ng + n;
            f32x4 acc0 = {0.f,0.f,0.f,0.f};
            f32x4 acc1 = acc0;
            #pragma unroll
            for (int k0 = 0; k0 < 8; ++k0){
                short8 wf = wfrag(nt, k0);
                acc0 = __builtin_amdgcn_mfma_f32_16x16x32_bf16(yb0[k0], wf, acc0, 0,0,0);
                acc1 = __builtin_amdgcn_mfma_f32_16x16x32_bf16(yb1[k0], wf, acc1, 0,0,0);
            }
            int v = h*128 + nt*16 + lr;
            float* op0 = out + (m0 + mg*32 + lg*4)*256 + v;
            op0[0]   = acc0[0];
            op0[256] = acc0[1];
            op0[512] = acc0[2];
            op0[768] = acc0[3];
            float* op1 = out + (m0 + mg*32 + 16 + lg*4)*256 + v;
            op1[0]   = acc1[0];
            op1[256] = acc1[1];
            op1[512] = acc1[2];
            op1[768] = acc1[3];
        }
    }
}

// --------------------------------------------------------------------------
extern "C" void kernel_launch(void* const* d_in, const int* in_sizes, int n_in,
                              void* d_out, int out_size, void* d_ws, size_t ws_size,
                              hipStream_t stream){
    const int*   idx   = (const int*)d_in[0];
    const float* embed = (const float*)d_in[1];
    const float* W_in  = (const float*)d_in[2];
    const float* W     = (const float*)d_in[3];
    const float* W1    = (const float*)d_in[4];
    const float* b1    = (const float*)d_in[5];
    const float* W2    = (const float*)d_in[6];
    const float* b2    = (const float*)d_in[7];
    const float* gamma = (const float*)d_in[8];
    const float* beta  = (const float*)d_in[9];

    char* ws = (char*)d_ws;
    float*  proj  = (float*)ws;                   // 256 KB fp32
    ushort* W1h   = (ushort*)(ws + 262144);       // 128 KB fp16
    ushort* W2h   = (ushort*)(ws + 393216);       // 128 KB fp16
    ushort* Eb    = (ushort*)(ws + 524288);       // 128 KB bf16
    ushort* Wh    = (ushort*)(ws + 655360);       // 128 KB fp16 W
    ushort* z1    = (ushort*)(ws + 1048576);      // 134.2 MB fp16 [B*T,256] pre-gelu
    if (ws_size < (size_t)135266304) return;      // ws too small -> recognizable absmax fail

    k_conv   <<<256, 256, 0, stream>>>(W1, W2, embed, W, W1h, W2h, Eb, Wh);
    k_proj   <<<256, 256, 0, stream>>>(embed, W_in, proj);
    k_recur  <<<256, 512, 0, stream>>>(idx, Wh, W1h, b1, proj, z1);
    k_readout<<<2048, 512, 0, stream>>>(z1, W2h, Eb, b2, gamma, beta, (float*)d_out);
}

// Round 23
// 339.405 us; speedup vs baseline: 2.1862x; 1.1390x over previous
//
#include <hip/hip_runtime.h>
#include <cstdint>

typedef __attribute__((ext_vector_type(8))) short short8;
typedef __attribute__((ext_vector_type(4))) float f32x4;

__device__ __forceinline__ ushort f2bf(float x){
    uint32_t u = __float_as_uint(x);
    u = (u + 0x7FFFu + ((u >> 16) & 1u)) >> 16;
    return (ushort)u;
}
__device__ __forceinline__ ushort f2h(float x){
    _Float16 h = (_Float16)x;
    return __builtin_bit_cast(ushort, h);
}

// ---- kernel 1: weight conversion (fp16 W, W1, W2; bf16 embed) ------------
__global__ void k_conv(const float* __restrict__ W1, const float* __restrict__ W2,
                       const float* __restrict__ Emb, const float* __restrict__ W,
                       ushort* __restrict__ W1h, ushort* __restrict__ W2h,
                       ushort* __restrict__ Eb, ushort* __restrict__ Wh){
    int i = blockIdx.x * 256 + threadIdx.x;   // grid 256 -> 65536
    W1h[i] = f2h(W1[i]);
    W2h[i] = f2h(W2[i]);
    Eb[i]  = f2bf(Emb[i]);
    Wh[i]  = f2h(W[i]);
}

// -------- kernel 2: proj[v][h] = sum_e embed[v,e]*W_in[h,e]  (fp32) -------
__global__ void k_proj(const float* __restrict__ emb, const float* __restrict__ Win,
                       float* __restrict__ proj){
    __shared__ __align__(16) float se[256];
    int v = blockIdx.x, h = threadIdx.x;
    se[h] = emb[v*256 + h];
    __syncthreads();
    const float* wr = Win + h*256;
    float a0=0.f,a1=0.f,a2=0.f,a3=0.f;
    #pragma unroll
    for (int e = 0; e < 256; e += 4){
        float4 w = *(const float4*)(wr + e);
        a0 = fmaf(w.x, se[e+0], a0);
        a1 = fmaf(w.y, se[e+1], a1);
        a2 = fmaf(w.z, se[e+2], a2);
        a3 = fmaf(w.w, se[e+3], a3);
    }
    proj[v*256 + h] = (a0+a1)+(a2+a3);
}

// ---- kernel 3: ESN recurrence + FUSED GEMM1, fp16, MFMA ------------------
// 256 blocks = (segment s in [0,32)) x (batch group pg in [0,8)), 1 block/CU.
// warmup=128 HW-verified. Critical path 192(+1) steps.
// GEMM1 (z1 = h @ W1^T + b1) reuses the H_t B-fragments; at STEP(T) the H
// buffer holds h_{T-1} so the result stores as z1[T-1] (T > tw).
// r23: WARMUP SPLIT - STEPW (recurrence only) runs t in [t0,tw): the GEMM1
// MFMAs produced dead values for 128 of 193 steps (r22 fusion cost ~15us,
// ~2/3 in warmup).
__global__ __launch_bounds__(512, 2) void k_recur(const int* __restrict__ idx,
        const ushort* Wh, const ushort* W1h, const float* __restrict__ b1,
        const float* proj, ushort* z1){
    __shared__ __align__(16) char Hl[2][8192];   // fp16 H[16][256], dbuf, swizzled
    const int tid  = threadIdx.x;
    const int wid  = tid >> 6;
    const int lane = tid & 63;
    const int lr   = lane & 15;        // batch col / A-row-in-tile
    const int lg   = lane >> 4;
    const int seg  = blockIdx.x >> 3;  // time segment 0..31
    const int pg   = blockIdx.x & 7;   // batch group 0..7
    const int t0   = (64*seg - 128 > 0) ? (64*seg - 128) : 0;
    const int t1   = 64*seg + 64;
    const int tw   = 64*seg;           // first written step

    // A-frags: W rows (recurrence) and W1 rows (fused GEMM1) for tiles
    // n0=2*wid, n1=2*wid+1 (fp16, 32 frags = 128 VGPR)
    short8 A0[8], A1[8], B0[8], B1[8];
    {
        const char* wb = (const char*)Wh  + (32*wid + lr)*512 + lg*16;
        const char* vb = (const char*)W1h + (32*wid + lr)*512 + lg*16;
        #pragma unroll
        for (int kk = 0; kk < 8; ++kk){
            A0[kk] = __builtin_bit_cast(short8, *(const uint4*)(wb + kk*64));
            A1[kk] = __builtin_bit_cast(short8, *(const uint4*)(wb + 16*512 + kk*64));
            B0[kk] = __builtin_bit_cast(short8, *(const uint4*)(vb + kk*64));
            B1[kk] = __builtin_bit_cast(short8, *(const uint4*)(vb + 16*512 + kk*64));
        }
    }

    char* Hb = &Hl[0][0];
    *(uint4*)(Hb + tid*16) = uint4{0,0,0,0};     // zero buffer 0 (8 KB)
    __syncthreads();

    const int mybat = pg*16 + lr;
    const int64_t idxbase = (int64_t)mybat * 2048;
    ushort* zrow = z1 + (size_t)mybat * 2048 * 256;
    const int hd0 = 32*wid + lg*4;               // tile0 quad base dim
    const int hd1 = hd0 + 16;

    float hp0[4] = {0.f,0.f,0.f,0.f}, hp1[4] = {0.f,0.f,0.f,0.f};
    const f32x4 bi0 = *(const f32x4*)(b1 + hd0);
    const f32x4 bi1 = *(const f32x4*)(b1 + hd1);

    int tok  = idx[idxbase + t0];
    int tok2 = idx[idxbase + ((t0+1 < 2048) ? t0+1 : 2047)];
    f32x4 u0 = *(const f32x4*)(proj + tok*256 + hd0);
    f32x4 u1 = *(const f32x4*)(proj + tok*256 + hd1);

// shared epilogue: tanh/leak + H-write + loop-carried updates
#define EPI(T, WO)                                                             \
        f32x4 u0n = *(const f32x4*)(proj + tok2*256 + hd0);                    \
        f32x4 u1n = *(const f32x4*)(proj + tok2*256 + hd1);                    \
        float hn0[4], hn1[4];                                                  \
        _Pragma("unroll")                                                      \
        for (int q = 0; q < 4; ++q){                                           \
            float p0 = ac0[q] + bc0[q];                                        \
            float e0 = __builtin_amdgcn_exp2f(p0 * 2.8853900817779268f);       \
            float r0 = __builtin_amdgcn_rcpf(e0 + 1.f);                        \
            hn0[q] = fmaf(0.7f, hp0[q], fmaf(-0.6f, r0, 0.3f));                \
            hp0[q] = hn0[q];                                                   \
            float p1 = ac1[q] + bc1[q];                                        \
            float e1 = __builtin_amdgcn_exp2f(p1 * 2.8853900817779268f);       \
            float r1 = __builtin_amdgcn_rcpf(e1 + 1.f);                        \
            hn1[q] = fmaf(0.7f, hp1[q], fmaf(-0.6f, r1, 0.3f));                \
            hp1[q] = hn1[q];                                                   \
        }                                                                      \
        uint2 pk0, pk1;                                                        \
        pk0.x = __builtin_bit_cast(uint, __builtin_amdgcn_cvt_pkrtz(hn0[0], hn0[1])); \
        pk0.y = __builtin_bit_cast(uint, __builtin_amdgcn_cvt_pkrtz(hn0[2], hn0[3])); \
        pk1.x = __builtin_bit_cast(uint, __builtin_amdgcn_cvt_pkrtz(hn1[0], hn1[1])); \
        pk1.y = __builtin_bit_cast(uint, __builtin_amdgcn_cvt_pkrtz(hn1[2], hn1[3])); \
        int wa0 = ((WO) + lr*512 + hd0*2) ^ (lr << 4);                         \
        int wa1 = ((WO) + lr*512 + hd1*2) ^ (lr << 4);                         \
        *(uint2*)(Hb + wa0) = pk0;                                             \
        *(uint2*)(Hb + wa1) = pk1;                                             \
        u0 = u0n; u1 = u1n; tok2 = tok3;                                       \
        asm volatile("s_waitcnt lgkmcnt(0)\n\ts_barrier" ::: "memory");

// warmup step: recurrence only (no GEMM1)
#define STEPW(T, RO, WO)                                                       \
    {                                                                          \
        int tok3 = idx[idxbase + (((T)+2 < 2048) ? (T)+2 : 2047)];             \
        f32x4 ac0 = u0, ac1 = u1;                                              \
        f32x4 bc0 = {0.f,0.f,0.f,0.f}, bc1 = {0.f,0.f,0.f,0.f};                \
        _Pragma("unroll")                                                      \
        for (int kk = 0; kk < 4; ++kk){                                        \
            int ra = ((RO) + lr*512 + kk*64 + lg*16) ^ (lr << 4);              \
            short8 Bf = __builtin_bit_cast(short8, *(const uint4*)(Hb + ra));  \
            ac0 = __builtin_amdgcn_mfma_f32_16x16x32_f16(A0[kk], Bf, ac0, 0,0,0);\
            ac1 = __builtin_amdgcn_mfma_f32_16x16x32_f16(A1[kk], Bf, ac1, 0,0,0);\
        }                                                                      \
        _Pragma("unroll")                                                      \
        for (int kk = 4; kk < 8; ++kk){                                        \
            int ra = ((RO) + lr*512 + kk*64 + lg*16) ^ (lr << 4);              \
            short8 Bf = __builtin_bit_cast(short8, *(const uint4*)(Hb + ra));  \
            bc0 = __builtin_amdgcn_mfma_f32_16x16x32_f16(A0[kk], Bf, bc0, 0,0,0);\
            bc1 = __builtin_amdgcn_mfma_f32_16x16x32_f16(A1[kk], Bf, bc1, 0,0,0);\
        }                                                                      \
        EPI(T, WO)                                                             \
    }

// payload step: recurrence + GEMM1 + z1[T-1] store
#define STEP(T, RO, WO)                                                        \
    {                                                                          \
        int tok3 = idx[idxbase + (((T)+2 < 2048) ? (T)+2 : 2047)];             \
        f32x4 ac0 = u0, ac1 = u1;                                              \
        f32x4 bc0 = {0.f,0.f,0.f,0.f}, bc1 = {0.f,0.f,0.f,0.f};                \
        f32x4 g0 = bi0, g1 = bi1;                                              \
        _Pragma("unroll")                                                      \
        for (int kk = 0; kk < 4; ++kk){                                        \
            int ra = ((RO) + lr*512 + kk*64 + lg*16) ^ (lr << 4);              \
            short8 Bf = __builtin_bit_cast(short8, *(const uint4*)(Hb + ra));  \
            ac0 = __builtin_amdgcn_mfma_f32_16x16x32_f16(A0[kk], Bf, ac0, 0,0,0);\
            ac1 = __builtin_amdgcn_mfma_f32_16x16x32_f16(A1[kk], Bf, ac1, 0,0,0);\
            g0  = __builtin_amdgcn_mfma_f32_16x16x32_f16(B0[kk], Bf, g0, 0,0,0);\
            g1  = __builtin_amdgcn_mfma_f32_16x16x32_f16(B1[kk], Bf, g1, 0,0,0);\
        }                                                                      \
        _Pragma("unroll")                                                      \
        for (int kk = 4; kk < 8; ++kk){                                        \
            int ra = ((RO) + lr*512 + kk*64 + lg*16) ^ (lr << 4);              \
            short8 Bf = __builtin_bit_cast(short8, *(const uint4*)(Hb + ra));  \
            bc0 = __builtin_amdgcn_mfma_f32_16x16x32_f16(A0[kk], Bf, bc0, 0,0,0);\
            bc1 = __builtin_amdgcn_mfma_f32_16x16x32_f16(A1[kk], Bf, bc1, 0,0,0);\
            g0  = __builtin_amdgcn_mfma_f32_16x16x32_f16(B0[kk], Bf, g0, 0,0,0);\
            g1  = __builtin_amdgcn_mfma_f32_16x16x32_f16(B1[kk], Bf, g1, 0,0,0);\
        }                                                                      \
        if ((T) > tw){   /* z1[T-1] = W1 @ h_{T-1} + b1 (time-aligned) */      \
            uint2 zk0, zk1;                                                    \
            zk0.x = __builtin_bit_cast(uint, __builtin_amdgcn_cvt_pkrtz(g0[0], g0[1])); \
            zk0.y = __builtin_bit_cast(uint, __builtin_amdgcn_cvt_pkrtz(g0[2], g0[3])); \
            zk1.x = __builtin_bit_cast(uint, __builtin_amdgcn_cvt_pkrtz(g1[0], g1[1])); \
            zk1.y = __builtin_bit_cast(uint, __builtin_amdgcn_cvt_pkrtz(g1[2], g1[3])); \
            *(uint2*)(zrow + (size_t)((T)-1)*256 + hd0) = zk0;                 \
            *(uint2*)(zrow + (size_t)((T)-1)*256 + hd1) = zk1;                 \
        }                                                                      \
        EPI(T, WO)                                                             \
    }

    for (int t = t0; t < tw; t += 2){   // warmup: (tw-t0) even
        STEPW(t,   0,    8192);
        STEPW(t+1, 8192, 0);
    }
    for (int t = tw; t < t1; t += 2){   // payload: 64 steps
        STEP(t,   0,    8192);
        STEP(t+1, 8192, 0);
    }
    STEP(t1, 0, 8192);   // epilogue: emits z1[t1-1]
#undef STEP
#undef STEPW
#undef EPI
}

// ---- kernel 4: readout tail: gelu(z1) @ W2.T + b2 -> LN -> @ embed.T -----
// r22 structure (HW-verified 222us). Phase 0 geluizes z1 fragment-wise with
// short liveness (load 16B -> gelu -> fp16 pack -> a_lds; same-thread R/W,
// no barrier). r23: gelu uses the folded TANH form (5 VALU + 2 trans per 2
// values vs erff's ~25; max dev 3e-4 < fp16 quantization already applied).
// GEMM2 fp16; LN + bf16 GEMM3 verbatim from r14.
__global__ __launch_bounds__(512) void k_readout(
        const ushort* __restrict__ z1,
        const ushort* __restrict__ W2h, const ushort* __restrict__ Eb,
        const float* __restrict__ b2,
        const float* __restrict__ gamma, const float* __restrict__ beta,
        float* __restrict__ out){
    __shared__ __align__(16) char w_lds[65536];   // staged weight half
    __shared__ __align__(16) char a_lds[65536];   // A1 / y tile: 128 x 256 x 2B
    __shared__ __align__(16) float4 ln_lds[8][16];

    const int tid  = threadIdx.x;
    const int wid  = tid >> 6;
    const int mg   = wid >> 1;
    const int ng   = wid & 1;
    const int lane = tid & 63;
    const int lr   = lane & 15;
    const int lg   = lane >> 4;
    const size_t m0 = (size_t)blockIdx.x * 128;
    const int ml0  = mg*32 + lr;
    const int ml1  = ml0 + 16;

    auto stage = [&](const ushort* src){
        #pragma unroll
        for (int i = 0; i < 8; ++i){
            int off = (i*512 + tid) * 16;
            uint4 v = *(const uint4*)((const char*)src + off);
            int row = off >> 9;
            *(uint4*)(w_lds + (off ^ ((row & 7) << 4))) = v;
        }
    };
    auto wfrag = [&](int n, int k0) -> short8 {
        int row  = n*16 + lr;
        int addr = (row << 9) + k0*64 + lg*16;
        addr ^= (row & 7) << 4;
        return __builtin_bit_cast(short8, *(const uint4*)(w_lds + addr));
    };
    auto afrag = [&](int ml, int k0) -> short8 {
        int addr = (ml << 9) + k0*64 + lg*16;
        addr ^= (ml & 7) << 4;
        return __builtin_bit_cast(short8, *(const uint4*)(a_lds + addr));
    };
    auto awrite = [&](int ml, int ecol, f32x4 v){
        ushort4 pk;
        pk.x = f2bf(v[0]); pk.y = f2bf(v[1]); pk.z = f2bf(v[2]); pk.w = f2bf(v[3]);
        int addr = (ml << 9) + ecol*2;
        addr ^= (ml & 7) << 4;
        *(ushort4*)(a_lds + addr) = pk;
    };
    // tanh-form gelu: g = x*(1 - rcp(exp2(x*(2.302110 + 0.102944*x^2)) + 1))
    auto gelu1 = [&](float x) -> float {
        float x2 = x*x;
        float c  = fmaf(0.10294404f, x2, 2.30211416f);
        float e  = __builtin_amdgcn_exp2f(x*c);
        float r  = __builtin_amdgcn_rcpf(e + 1.f);
        return fmaf(-x, r, x);
    };
    // gelu on one packed 16B fragment (8 fp16), repack fp16
    auto gelupk = [&](uint4 z) -> uint4 {
        uint4 r;
        #pragma unroll
        for (int q = 0; q < 4; ++q){
            uint w = ((const uint*)&z)[q];
            float xa = (float)__builtin_bit_cast(_Float16, (ushort)(w & 0xffffu));
            float xb = (float)__builtin_bit_cast(_Float16, (ushort)(w >> 16));
            ((uint*)&r)[q] = __builtin_bit_cast(uint,
                __builtin_amdgcn_cvt_pkrtz(gelu1(xa), gelu1(xb)));
        }
        return r;
    };

    // ---- Phase 0: gelu(z1) -> a_lds (fp16), per-frag short liveness ----
    {
        const char* p0 = (const char*)(z1 + (m0 + ml0)*256) + lg*16;
        const char* p1 = (const char*)(z1 + (m0 + ml1)*256) + lg*16;
        #pragma unroll
        for (int k0 = 0; k0 < 8; ++k0){
            uint4 g0 = gelupk(*(const uint4*)(p0 + k0*64));
            int a0 = ((ml0 << 9) + k0*64 + lg*16) ^ ((ml0 & 7) << 4);
            *(uint4*)(a_lds + a0) = g0;
            uint4 g1 = gelupk(*(const uint4*)(p1 + k0*64));
            int a1 = ((ml1 << 9) + k0*64 + lg*16) ^ ((ml1 & 7) << 4);
            *(uint4*)(a_lds + a1) = g1;
        }
    }

    // ================= GEMM2 (fp16): o = A1 @ W2.T + b2 =================
    short8 ab0[8], ab1[8];
    #pragma unroll
    for (int k0 = 0; k0 < 8; ++k0){ ab0[k0] = afrag(ml0, k0); ab1[k0] = afrag(ml1, k0); }
    f32x4 oacc0[8], oacc1[8];
    #pragma unroll
    for (int h = 0; h < 2; ++h){
        __syncthreads();
        stage(W2h + h*128*256);
        __syncthreads();
        #pragma unroll
        for (int n = 0; n < 4; ++n){
            int nt = 4*ng + n;
            int eb = h*128 + nt*16;
            float4 bi = *(const float4*)(b2 + eb + lg*4);
            f32x4 acc0 = {bi.x, bi.y, bi.z, bi.w};
            f32x4 acc1 = acc0;
            #pragma unroll
            for (int k0 = 0; k0 < 8; ++k0){
                short8 wf = wfrag(nt, k0);
                acc0 = __builtin_amdgcn_mfma_f32_16x16x32_f16(wf, ab0[k0], acc0, 0,0,0);
                acc1 = __builtin_amdgcn_mfma_f32_16x16x32_f16(wf, ab1[k0], acc1, 0,0,0);
            }
            oacc0[h*4+n] = acc0;
            oacc1[h*4+n] = acc1;
        }
    }

    // ====== LayerNorm over e2: in-wave shfl + cross-wave (ng pair) LDS ======
    {
        float s0 = 0.f, q0 = 0.f, s1 = 0.f, q1 = 0.f;
        #pragma unroll
        for (int i = 0; i < 8; ++i){
            #pragma unroll
            for (int q = 0; q < 4; ++q){
                float x = oacc0[i][q]; s0 += x; q0 += x*x;
                float y = oacc1[i][q]; s1 += y; q1 += y*y;
            }
        }
        s0 += __shfl_xor(s0, 16); q0 += __shfl_xor(q0, 16);
        s0 += __shfl_xor(s0, 32); q0 += __shfl_xor(q0, 32);
        s1 += __shfl_xor(s1, 16); q1 += __shfl_xor(q1, 16);
        s1 += __shfl_xor(s1, 32); q1 += __shfl_xor(q1, 32);
        __syncthreads();                     // all waves done reading w_lds h1
        if (lg == 0) ln_lds[wid][lr] = float4{s0, q0, s1, q1};
        __syncthreads();
        float4 pp = ln_lds[wid ^ 1][lr];
        s0 += pp.x; q0 += pp.y; s1 += pp.z; q1 += pp.w;
        float mu0   = s0 * (1.f/256.f);
        float var0  = q0 * (1.f/256.f) - mu0*mu0;
        float rstd0 = rsqrtf(var0 + 1e-5f);
        float mu1   = s1 * (1.f/256.f);
        float var1  = q1 * (1.f/256.f) - mu1*mu1;
        float rstd1 = rsqrtf(var1 + 1e-5f);
        #pragma unroll
        for (int i = 0; i < 8; ++i){
            int h = i >> 2, n = i & 3;
            int ecol = h*128 + (4*ng + n)*16 + lg*4;
            float4 g4 = *(const float4*)(gamma + ecol);
            float4 t4 = *(const float4*)(beta + ecol);
            f32x4 y0, y1;
            y0[0] = (oacc0[i][0]-mu0)*rstd0*g4.x + t4.x;
            y0[1] = (oacc0[i][1]-mu0)*rstd0*g4.y + t4.y;
            y0[2] = (oacc0[i][2]-mu0)*rstd0*g4.z + t4.z;
            y0[3] = (oacc0[i][3]-mu0)*rstd0*g4.w + t4.w;
            y1[0] = (oacc1[i][0]-mu1)*rstd1*g4.x + t4.x;
            y1[1] = (oacc1[i][1]-mu1)*rstd1*g4.y + t4.y;
            y1[2] = (oacc1[i][2]-mu1)*rstd1*g4.z + t4.z;
            y1[3] = (oacc1[i][3]-mu1)*rstd1*g4.w + t4.w;
            awrite(ml0, ecol, y0);
            awrite(ml1, ecol, y1);
        }
    }

    // ================= GEMM3 (bf16): logits = y @ embed.T =================
    __syncthreads();
    short8 yb0[8], yb1[8];
    #pragma unroll
    for (int k0 = 0; k0 < 8; ++k0){ yb0[k0] = afrag(ml0, k0); yb1[k0] = afrag(ml1, k0); }
    #pragma unroll
    for (int h = 0; h < 2; ++h){
        __syncthreads();
        stage(Eb + h*128*256);
        __syncthreads();
        #pragma unroll
        for (int n = 0; n < 4; ++n){
            int nt = 4*ng + n;
            f32x4 acc0 = {0.f,0.f,0.f,0.f};
            f32x4 acc1 = acc0;
            #pragma unroll
            for (int k0 = 0; k0 < 8; ++k0){
                short8 wf = wfrag(nt, k0);
                acc0 = __builtin_amdgcn_mfma_f32_16x16x32_bf16(yb0[k0], wf, acc0, 0,0,0);
                acc1 = __builtin_amdgcn_mfma_f32_16x16x32_bf16(yb1[k0], wf, acc1, 0,0,0);
            }
            int v = h*128 + nt*16 + lr;
            float* op0 = out + (m0 + mg*32 + lg*4)*256 + v;
            op0[0]   = acc0[0];
            op0[256] = acc0[1];
            op0[512] = acc0[2];
            op0[768] = acc0[3];
            float* op1 = out + (m0 + mg*32 + 16 + lg*4)*256 + v;
            op1[0]   = acc1[0];
            op1[256] = acc1[1];
            op1[512] = acc1[2];
            op1[768] = acc1[3];
        }
    }
}

// --------------------------------------------------------------------------
extern "C" void kernel_launch(void* const* d_in, const int* in_sizes, int n_in,
                              void* d_out, int out_size, void* d_ws, size_t ws_size,
                              hipStream_t stream){
    const int*   idx   = (const int*)d_in[0];
    const float* embed = (const float*)d_in[1];
    const float* W_in  = (const float*)d_in[2];
    const float* W     = (const float*)d_in[3];
    const float* W1    = (const float*)d_in[4];
    const float* b1    = (const float*)d_in[5];
    const float* W2    = (const float*)d_in[6];
    const float* b2    = (const float*)d_in[7];
    const float* gamma = (const float*)d_in[8];
    const float* beta  = (const float*)d_in[9];

    char* ws = (char*)d_ws;
    float*  proj  = (float*)ws;                   // 256 KB fp32
    ushort* W1h   = (ushort*)(ws + 262144);       // 128 KB fp16
    ushort* W2h   = (ushort*)(ws + 393216);       // 128 KB fp16
    ushort* Eb    = (ushort*)(ws + 524288);       // 128 KB bf16
    ushort* Wh    = (ushort*)(ws + 655360);       // 128 KB fp16 W
    ushort* z1    = (ushort*)(ws + 1048576);      // 134.2 MB fp16 [B*T,256] pre-gelu
    if (ws_size < (size_t)135266304) return;      // ws too small -> recognizable absmax fail

    k_conv   <<<256, 256, 0, stream>>>(W1, W2, embed, W, W1h, W2h, Eb, Wh);
    k_proj   <<<256, 256, 0, stream>>>(embed, W_in, proj);
    k_recur  <<<256, 512, 0, stream>>>(idx, Wh, W1h, b1, proj, z1);
    k_readout<<<2048, 512, 0, stream>>>(z1, W2h, Eb, b2, gamma, beta, (float*)d_out);
}